// Round 5
// baseline (36.048 us; speedup 1.0000x reference)
//
#include <hip/hip_runtime.h>

typedef _Float16 f16x8 __attribute__((ext_vector_type(8)));
typedef _Float16 f16x4 __attribute__((ext_vector_type(4)));
typedef float f32x4 __attribute__((ext_vector_type(4)));

#define B_N 8192
#define K_N 256
#define DIM_N 1024

// ---------------- prep_w: per class k -> Uf=f16(Dinv-1), Wf=f16(-2c*Dinv), ec[k]=-0.5*(logdet+c2) ----------------
__global__ __launch_bounds__(256) void prep_w(const float* __restrict__ Dm,
                                              const float* __restrict__ Cm,
                                              _Float16* __restrict__ Uf,
                                              _Float16* __restrict__ Wf,
                                              float* __restrict__ ec) {
    const int k = blockIdx.x, t = threadIdx.x;
    const int d = t * 4;
    const float4 dv = *(const float4*)(Dm + (size_t)k * DIM_N + d);
    const float4 cv = *(const float4*)(Cm + (size_t)k * DIM_N + d);
    float dd[4] = {dv.x, dv.y, dv.z, dv.w};
    float cc[4] = {cv.x, cv.y, cv.z, cv.w};
    f16x4 uo, wo;
    float llog = 0.f, lc2 = 0.f;
#pragma unroll
    for (int i = 0; i < 4; ++i) {
        float da = fabsf(dd[i]) + 1e-4f;
        float dinv = 1.0f / da;
        llog += logf(da);
        lc2 += cc[i] * cc[i] * dinv;
        uo[i] = (_Float16)(dinv - 1.0f);
        wo[i] = (_Float16)(-2.0f * cc[i] * dinv);
    }
    *(f16x4*)(Uf + (size_t)k * DIM_N + d) = uo;
    *(f16x4*)(Wf + (size_t)k * DIM_N + d) = wo;
    float both = llog + lc2;
#pragma unroll
    for (int m = 1; m <= 32; m <<= 1) both += __shfl_xor(both, m, 64);
    __shared__ float sb[4];
    if ((t & 63) == 0) sb[t >> 6] = both;
    __syncthreads();
    if (t == 0) ec[k] = -0.5f * (sb[0] + sb[1] + sb[2] + sb[3]);
}

// ---------------- gmm_gemm: S = x^2*U + x*W  (64x128 tile, both products, one acc) ----------------
// grid 256 = 128 row-panels x 2 col-panels. 8 waves (2 wr x 4 wc), wave-tile 32x32.
// LDS per buffer (48KB): A2 @0 (64x64), XH @8K, U @16K (128x64), W @32K. Dbuf stride 48K.
// A cell(row,s) = s*1024 + ((row^s)&63)*16 ; B cell(col,s) = s*2048 + ((col^s)&127)*16.
__global__ __launch_bounds__(512, 1)
void gmm_gemm(const float* __restrict__ x,
              const _Float16* __restrict__ Uf,
              const _Float16* __restrict__ Wf,
              float* __restrict__ S) {
    __shared__ __align__(16) char lds[98304];

    const int tid = threadIdx.x;
    const int wave = tid >> 6, lane = tid & 63, l15 = lane & 15, g = lane >> 4;
    const int wr = wave >> 2, wc = wave & 3;

    // XCD-aware decode: both col-panels of a row-panel land on the same XCD.
    const int bid = blockIdx.x;
    const int xcd = bid & 7, idx = bid >> 3;
    const int colp = idx & 1;
    const int rowp = (idx >> 1) * 8 + xcd;   // 0..127
    const int bRow = rowp * 64;
    const int bCol = colp * 128;

    // x staging: thread -> row = tid>>3 (0..63), slot s = tid&7 (8 dims)
    const int xrow = tid >> 3, xs = tid & 7;
    const float* xp = x + (size_t)(bRow + xrow) * DIM_N + xs * 8;
    const int aWr = xs * 1024 + (((xrow ^ xs) & 63) << 4);
    // W staging: thread -> row = tid>>2 (0..127), slots s = 2*(tid&3)+{0,1}
    const int wrow = tid >> 2, wq = tid & 3;
    const _Float16* up = Uf + (size_t)(bCol + wrow) * DIM_N + wq * 16;
    const _Float16* wp = Wf + (size_t)(bCol + wrow) * DIM_N + wq * 16;
    int bWr[2];
#pragma unroll
    for (int j = 0; j < 2; ++j) {
        const int s = wq * 2 + j;
        bWr[j] = s * 2048 + (((wrow ^ s) & 127) << 4);
    }

    // frag read offsets
    int aRd[2][2], bRd[2][2];
#pragma unroll
    for (int k2 = 0; k2 < 2; ++k2) {
        const int s = k2 * 4 + g;
#pragma unroll
        for (int m = 0; m < 2; ++m) {
            const int row = wr * 32 + m * 16 + l15;
            aRd[m][k2] = s * 1024 + (((row ^ s) & 63) << 4);
        }
#pragma unroll
        for (int n = 0; n < 2; ++n) {
            const int col = wc * 32 + n * 16 + l15;
            bRd[n][k2] = s * 2048 + (((col ^ s) & 127) << 4);
        }
    }

    f32x4 acc[2][2];
#pragma unroll
    for (int m = 0; m < 2; ++m)
#pragma unroll
        for (int n = 0; n < 2; ++n) {
            f32x4 z = {0.f, 0.f, 0.f, 0.f};
            acc[m][n] = z;
        }

    float4 xv[2][2];            // [bank][half] 8 floats
    f16x8 uv[2][2], wv[2][2];   // [bank][slot]

    auto loadX = [&](int bank, int c) {
        xv[bank][0] = *(const float4*)(xp + c * 64);
        xv[bank][1] = *(const float4*)(xp + c * 64 + 4);
    };
    auto loadW = [&](int bank, int c) {
        uv[bank][0] = *(const f16x8*)(up + c * 64);
        uv[bank][1] = *(const f16x8*)(up + c * 64 + 8);
        wv[bank][0] = *(const f16x8*)(wp + c * 64);
        wv[bank][1] = *(const f16x8*)(wp + c * 64 + 8);
    };
    auto stage = [&](int base, int bank) {
        float f[8] = {xv[bank][0].x, xv[bank][0].y, xv[bank][0].z, xv[bank][0].w,
                      xv[bank][1].x, xv[bank][1].y, xv[bank][1].z, xv[bank][1].w};
        _Float16 h2[8], hx[8];
#pragma unroll
        for (int i = 0; i < 8; ++i) {
            h2[i] = (_Float16)(f[i] * f[i]);
            hx[i] = (_Float16)f[i];
        }
        *(f16x8*)(lds + base + aWr) = *(const f16x8*)&h2[0];
        *(f16x8*)(lds + base + 8192 + aWr) = *(const f16x8*)&hx[0];
        *(f16x8*)(lds + base + 16384 + bWr[0]) = uv[bank][0];
        *(f16x8*)(lds + base + 16384 + bWr[1]) = uv[bank][1];
        *(f16x8*)(lds + base + 32768 + bWr[0]) = wv[bank][0];
        *(f16x8*)(lds + base + 32768 + bWr[1]) = wv[bank][1];
    };

    // ---- prologue: chunks 0,1 in flight; stage chunk 0 ----
    loadX(0, 0); loadW(0, 0);
    loadX(1, 1); loadW(1, 1);
    stage(0, 0);
    asm volatile("s_waitcnt lgkmcnt(0)" ::: "memory");
    __builtin_amdgcn_s_barrier();
    __builtin_amdgcn_sched_barrier(0);

#pragma unroll
    for (int c = 0; c < 16; ++c) {
        const int cur = c & 1, nxt = cur ^ 1;
        const int bCur = cur * 49152, bNxt = nxt * 49152;
        // issue loads for chunk c+2 (bank cur is free; loads stay in flight across barriers)
        if (c < 14) { loadX(cur, c + 2); loadW(cur, c + 2); }
        // frags of chunk c
        f16x8 a2f[2][2], axf[2][2], buf[2][2], bwf[2][2];
#pragma unroll
        for (int k2 = 0; k2 < 2; ++k2) {
#pragma unroll
            for (int m = 0; m < 2; ++m) {
                a2f[m][k2] = *(const f16x8*)(lds + bCur + aRd[m][k2]);
                axf[m][k2] = *(const f16x8*)(lds + bCur + 8192 + aRd[m][k2]);
            }
#pragma unroll
            for (int n = 0; n < 2; ++n) {
                buf[n][k2] = *(const f16x8*)(lds + bCur + 16384 + bRd[n][k2]);
                bwf[n][k2] = *(const f16x8*)(lds + bCur + 32768 + bRd[n][k2]);
            }
        }
        __builtin_amdgcn_s_setprio(1);
#pragma unroll
        for (int m = 0; m < 2; ++m)
#pragma unroll
            for (int n = 0; n < 2; ++n)
#pragma unroll
                for (int k2 = 0; k2 < 2; ++k2) {
                    acc[m][n] = __builtin_amdgcn_mfma_f32_16x16x32_f16(a2f[m][k2], buf[n][k2], acc[m][n], 0, 0, 0);
                    acc[m][n] = __builtin_amdgcn_mfma_f32_16x16x32_f16(axf[m][k2], bwf[n][k2], acc[m][n], 0, 0, 0);
                }
        __builtin_amdgcn_s_setprio(0);
        if (c < 15) {
            stage(bNxt, nxt);
            asm volatile("s_waitcnt lgkmcnt(0)" ::: "memory");
            __builtin_amdgcn_s_barrier();
            __builtin_amdgcn_sched_barrier(0);
        }
    }

    // ---- epilogue: store raw acc (dist_sq - c2 - rowconst) ----
#pragma unroll
    for (int m = 0; m < 2; ++m) {
        const int rb = bRow + wr * 32 + m * 16 + g * 4;
        const int cb = bCol + wc * 32 + l15;
#pragma unroll
        for (int j = 0; j < 4; ++j) {
            float* p = S + (size_t)(rb + j) * K_N + cb;
            p[0] = acc[m][0][j];
            p[16] = acc[m][1][j];
        }
    }
}

// ---------------- gmm_soft: out = softmax_k(-0.5*S + ec[k]) per row, in place ----------------
__global__ __launch_bounds__(256)
void gmm_soft(float* __restrict__ S, const float* __restrict__ ecg) {
    const int tid = threadIdx.x;
    const int wave = tid >> 6, lane = tid & 63;
    const int r = blockIdx.x * 4 + wave;
    const int k0 = lane * 4;
    float4 s = *(const float4*)(S + (size_t)r * K_N + k0);
    float4 cv = *(const float4*)(ecg + k0);
    float e[4] = {fmaf(-0.5f, s.x, cv.x), fmaf(-0.5f, s.y, cv.y),
                  fmaf(-0.5f, s.z, cv.z), fmaf(-0.5f, s.w, cv.w)};
    float m = fmaxf(fmaxf(e[0], e[1]), fmaxf(e[2], e[3]));
#pragma unroll
    for (int msk = 1; msk <= 32; msk <<= 1) m = fmaxf(m, __shfl_xor(m, msk, 64));
    float p[4], sum = 0.f;
#pragma unroll
    for (int j = 0; j < 4; ++j) {
        p[j] = __expf(e[j] - m);
        sum += p[j];
    }
#pragma unroll
    for (int msk = 1; msk <= 32; msk <<= 1) sum += __shfl_xor(sum, msk, 64);
    const float inv = 1.0f / sum;
    *(float4*)(S + (size_t)r * K_N + k0) = make_float4(p[0] * inv, p[1] * inv, p[2] * inv, p[3] * inv);
}

extern "C" void kernel_launch(void* const* d_in, const int* in_sizes, int n_in,
                              void* d_out, int out_size, void* d_ws, size_t ws_size,
                              hipStream_t stream) {
    const float* x = (const float*)d_in[0];
    const float* cen = (const float*)d_in[1];
    const float* Dm = (const float*)d_in[2];
    float* out = (float*)d_out;

    char* ws = (char*)d_ws;
    _Float16* Uf = (_Float16*)(ws);                 // 512 KB
    _Float16* Wf = (_Float16*)(ws + 524288);        // 512 KB
    float* ec = (float*)(ws + 1048576);             // 1 KB

    prep_w<<<dim3(K_N), dim3(256), 0, stream>>>(Dm, cen, Uf, Wf, ec);
    gmm_gemm<<<dim3(256), dim3(512), 0, stream>>>(x, Uf, Wf, out);
    gmm_soft<<<dim3(B_N / 4), dim3(256), 0, stream>>>(out, ec);
}